// Round 3
// baseline (271.765 us; speedup 1.0000x reference)
//
#include <hip/hip_runtime.h>

#define NROW 6
#define NCOL 6
#define BATCH 1024
#define NSITE 36

// LDS bank swizzle on the dword index: XOR bits [4:2] with bits [7:5].
// Bits [1:0] untouched -> quads stay contiguous & 16B-aligned. Offsets that
// are multiples of 1024 dwords (4 KiB: g/gp planes, za*256? no - za*256 is
// bits>=8, zb*1024, planes 4096) do not touch bits [7:5] of the swizzled
// base patterns used here, so they commute with SW and fold into ds offset
// immediates. SW(0)==0; bijective.
__device__ __forceinline__ int SW(int d) { return d ^ (((d >> 5) & 7) << 2); }

// Wave-uniform scalar-memory pointer: address_space(4) = AMDGPU constant.
// Uniform-index float loads merge into s_load_dwordx16 (SMEM pipe).
typedef const float __attribute__((address_space(4))) * fcp;

__device__ __forceinline__ fcp msel(const float* Tm, int step,
                                    unsigned long long sm) {
    int spin = (int)((sm >> step) & 1ull);
    return (fcp)(unsigned long long)(const void*)
        (Tm + (size_t)(step * 2 + spin) * 256);
}

__device__ __forceinline__ float4 ldq(const float* p, int byteoff) {
    return *(const float4*)((const char*)p + byteoff);
}
__device__ __forceinline__ void stw(float* p, int byteoff, float v) {
    *(float*)((char*)p + byteoff) = v;
}

// Pre-transpose T[site][spin][u=x][r=gp][d=z][l=g] into
// Tm[(site*2+spin)*256 + (gp*4+z)*16 + (g*4+x)]  (73,728 B in d_ws).
__global__ void peps_reorder_kernel(const float* __restrict__ T,
                                    float* __restrict__ Tm)
{
    int idx = blockIdx.x * 256 + threadIdx.x;   // [0, 18432)
    if (idx >= NSITE * 2 * 256) return;
    int i  = idx & 15;          // i = g*4 + x
    int o  = (idx >> 4) & 15;   // o = gp*4 + z
    int sp = (idx >> 8) & 1;
    int st = idx >> 9;
    int g = i >> 2, x = i & 3, gp = o >> 2, z = o & 3;
    Tm[idx] = T[st * 512 + sp * 256 + x * 64 + gp * 16 + z * 4 + g];
}

// ============ Rotation-layout fused phases (R3) ============
// State between phases: planes g*4096 + s, spectators dense at stride 1.
// A fused pair reads digits (xa@1, xb@4), spectators sp@16 (thread t=sp:
// 16 CONSECUTIVE dwords at 16t per g-plane = 4 ds_read_b128), and writes
// (za@256, zb@1024) with spectators at stride 1 (scalar writes at t+const,
// const folds into the ds offset immediate). Algebra == R2's verified
// mid_first/mid_pair; only LDS indexing differs.

// Fused (r,0)+(r,1): GIN=1 (plane 0 only). 256 MACs (V) + 1024 (out).
__device__ __forceinline__ void p1_mid(const float* __restrict__ S,
                                       float* __restrict__ D,
                                       fcp Ma, fcp Mb,
                                       const int* __restrict__ RA, int WAb)
{
    float in_[4][4];                       // [xb][xa]
    #pragma unroll
    for (int q = 0; q < 4; ++q) {
        float4 v = ldq(S, RA[q]);
        in_[q][0] = v.x; in_[q][1] = v.y; in_[q][2] = v.z; in_[q][3] = v.w;
    }
    float V[4][4][4];                      // [gp][za][xb]
    #pragma unroll
    for (int gp = 0; gp < 4; ++gp)
        #pragma unroll
        for (int za = 0; za < 4; ++za) {
            const int mb = (gp * 4 + za) * 16;
            #pragma unroll
            for (int xb = 0; xb < 4; ++xb) {
                float a = 0.f;
                #pragma unroll
                for (int xa = 0; xa < 4; ++xa)
                    a += Ma[mb + xa] * in_[xb][xa];
                V[gp][za][xb] = a;
            }
        }
    #pragma unroll
    for (int gq = 0; gq < 4; ++gq)
        #pragma unroll
        for (int zb = 0; zb < 4; ++zb) {
            const int mb = (gq * 4 + zb) * 16;
            #pragma unroll
            for (int za = 0; za < 4; ++za) {
                float a = 0.f;
                #pragma unroll
                for (int gp = 0; gp < 4; ++gp)
                    #pragma unroll
                    for (int xb = 0; xb < 4; ++xb)
                        a += Mb[mb + gp * 4 + xb] * V[gp][za][xb];
                stw(D, WAb + gq * 16384 + zb * 4096 + za * 1024, a);
            }
        }
}

// Fused (r,c)+(r,c+1), full GIN=4; LAST=true for (r,4)+(r,5) (GOUT=1,
// result to plane 0 only). 1024 + 1024 (or 256) MACs per thread.
template<bool LAST>
__device__ __forceinline__ void p2_mid(const float* __restrict__ S,
                                       float* __restrict__ D,
                                       fcp Ma, fcp Mb,
                                       const int* __restrict__ RA, int WAb)
{
    float in_[4][4][4];                    // [g][xb][xa]
    #pragma unroll
    for (int g = 0; g < 4; ++g)
        #pragma unroll
        for (int q = 0; q < 4; ++q) {
            float4 v = ldq(S, RA[q] + g * 16384);
            in_[g][q][0] = v.x; in_[g][q][1] = v.y;
            in_[g][q][2] = v.z; in_[g][q][3] = v.w;
        }
    float V[4][4][4];                      // [gp][za][xb]
    #pragma unroll
    for (int gp = 0; gp < 4; ++gp)
        #pragma unroll
        for (int za = 0; za < 4; ++za) {
            const int mb = (gp * 4 + za) * 16;
            #pragma unroll
            for (int xb = 0; xb < 4; ++xb) {
                float a = 0.f;
                #pragma unroll
                for (int g = 0; g < 4; ++g)
                    #pragma unroll
                    for (int xa = 0; xa < 4; ++xa)
                        a += Ma[mb + g * 4 + xa] * in_[g][xb][xa];
                V[gp][za][xb] = a;
            }
        }
    #pragma unroll
    for (int gq = 0; gq < (LAST ? 1 : 4); ++gq)
        #pragma unroll
        for (int zb = 0; zb < 4; ++zb) {
            const int mb = (gq * 4 + zb) * 16;
            #pragma unroll
            for (int za = 0; za < 4; ++za) {
                float a = 0.f;
                #pragma unroll
                for (int gp = 0; gp < 4; ++gp)
                    #pragma unroll
                    for (int xb = 0; xb < 4; ++xb)
                        a += Mb[mb + gp * 4 + xb] * V[gp][za][xb];
                stw(D, WAb + gq * 16384 + zb * 4096 + za * 1024, a);
            }
        }
}

// Row 0, phase 1: steps (0,0..0,3) chained; 64 threads t=(gp3,z3,z2).
// V1 is wave-uniform (pure M products); per-thread slice written as quads
// at d = gp3*4096 + 64*z3 + 16*z2 + 4*z1 (+z0). Tiny work (<600 MACs/thr).
__device__ __forceinline__ void r0a(float* __restrict__ D, fcp M0, fcp M1,
                                    fcp M2, fcp M3, int t)
{
    const int gp3 = t >> 4, z3 = (t >> 2) & 3, z2 = t & 3;
    float V1[4][4][4];                     // [gp1][z1][z0]
    #pragma unroll
    for (int gp1 = 0; gp1 < 4; ++gp1)
        #pragma unroll
        for (int z1 = 0; z1 < 4; ++z1) {
            const int mb = (gp1 * 4 + z1) * 16;
            #pragma unroll
            for (int z0 = 0; z0 < 4; ++z0) {
                float a = 0.f;
                #pragma unroll
                for (int gp = 0; gp < 4; ++gp)
                    a += M1[mb + gp * 4] * M0[(gp * 4 + z0) * 16];
                V1[gp1][z1][z0] = a;
            }
        }
    float V2[4][4][4];                     // [gp2][z1][z0] (z2 fixed = own)
    #pragma unroll
    for (int gp2 = 0; gp2 < 4; ++gp2) {
        const int mb = (gp2 * 4 + z2) * 16;   // per-thread index -> v-load
        #pragma unroll
        for (int z1 = 0; z1 < 4; ++z1)
            #pragma unroll
            for (int z0 = 0; z0 < 4; ++z0) {
                float a = 0.f;
                #pragma unroll
                for (int gp1 = 0; gp1 < 4; ++gp1)
                    a += M2[mb + gp1 * 4] * V1[gp1][z1][z0];
                V2[gp2][z1][z0] = a;
            }
    }
    const int mb3 = (gp3 * 4 + z3) * 16;
    #pragma unroll
    for (int z1 = 0; z1 < 4; ++z1) {
        float o[4];
        #pragma unroll
        for (int z0 = 0; z0 < 4; ++z0) {
            float a = 0.f;
            #pragma unroll
            for (int gp2 = 0; gp2 < 4; ++gp2)
                a += M3[mb3 + gp2 * 4] * V2[gp2][z1][z0];
            o[z0] = a;
        }
        const int d = gp3 * 4096 + 64 * z3 + 16 * z2 + 4 * z1;
        *(float4*)((char*)D + 4 * SW(d)) = make_float4(o[0], o[1], o[2], o[3]);
    }
}

// Row 0, phase 2: fused (0,4)+(0,5); 256 threads, 4 scalar reads (g-planes),
// 16 scalar writes into (z4@256, z5@1024) of plane 0. 128 MACs/thread.
__device__ __forceinline__ void r0b(const float* __restrict__ S,
                                    float* __restrict__ D, fcp M4, fcp M5,
                                    int WAb)
{
    float u[4];
    #pragma unroll
    for (int g = 0; g < 4; ++g)
        u[g] = *(const float*)((const char*)S + WAb + g * 16384);
    float V[4][4];                         // [gp][z4]
    #pragma unroll
    for (int gp = 0; gp < 4; ++gp)
        #pragma unroll
        for (int z4 = 0; z4 < 4; ++z4) {
            float a = 0.f;
            #pragma unroll
            for (int g = 0; g < 4; ++g)
                a += M4[(gp * 4 + z4) * 16 + g * 4] * u[g];
            V[gp][z4] = a;
        }
    #pragma unroll
    for (int z5 = 0; z5 < 4; ++z5)
        #pragma unroll
        for (int z4 = 0; z4 < 4; ++z4) {
            float a = 0.f;
            #pragma unroll
            for (int gp = 0; gp < 4; ++gp)
                a += M5[z5 * 16 + gp * 4] * V[gp][z4];
            stw(D, WAb + z5 * 4096 + z4 * 1024, a);
        }
}

// Row 5, phase 1: fused (5,0)+(5,1) (ZS=1); 256 threads; writes gp'-planes.
__device__ __forceinline__ void r5a(const float* __restrict__ S,
                                    float* __restrict__ D, fcp Ma, fcp Mb,
                                    const int* __restrict__ RA, int WAb)
{
    float in_[4][4];                       // [x1=q][x0]
    #pragma unroll
    for (int q = 0; q < 4; ++q) {
        float4 v = ldq(S, RA[q]);
        in_[q][0] = v.x; in_[q][1] = v.y; in_[q][2] = v.z; in_[q][3] = v.w;
    }
    float A[4][4];                         // [gp][x1]
    #pragma unroll
    for (int gp = 0; gp < 4; ++gp)
        #pragma unroll
        for (int x1 = 0; x1 < 4; ++x1) {
            float a = 0.f;
            #pragma unroll
            for (int x0 = 0; x0 < 4; ++x0)
                a += Ma[gp * 64 + x0] * in_[x1][x0];
            A[gp][x1] = a;
        }
    #pragma unroll
    for (int gq = 0; gq < 4; ++gq) {
        float a = 0.f;
        #pragma unroll
        for (int gp = 0; gp < 4; ++gp)
            #pragma unroll
            for (int x1 = 0; x1 < 4; ++x1)
                a += Mb[gq * 64 + gp * 4 + x1] * A[gp][x1];
        stw(D, WAb + gq * 16384, a);
    }
}

// Row 5, phase 2: fused (5,2)+(5,3); 16 threads t=(x4 + 4*x5).
__device__ __forceinline__ void r5b(const float* __restrict__ S,
                                    float* __restrict__ D, fcp Ma, fcp Mb,
                                    const int* __restrict__ RA, int WAb)
{
    float in_[4][4][4];                    // [g][x3=q][x2]
    #pragma unroll
    for (int g = 0; g < 4; ++g)
        #pragma unroll
        for (int q = 0; q < 4; ++q) {
            float4 v = ldq(S, RA[q] + g * 16384);
            in_[g][q][0] = v.x; in_[g][q][1] = v.y;
            in_[g][q][2] = v.z; in_[g][q][3] = v.w;
        }
    float C[4][4];                         // [gp][x3]
    #pragma unroll
    for (int gp = 0; gp < 4; ++gp)
        #pragma unroll
        for (int x3 = 0; x3 < 4; ++x3) {
            float a = 0.f;
            #pragma unroll
            for (int g = 0; g < 4; ++g)
                #pragma unroll
                for (int x2 = 0; x2 < 4; ++x2)
                    a += Ma[gp * 64 + g * 4 + x2] * in_[g][x3][x2];
            C[gp][x3] = a;
        }
    #pragma unroll
    for (int gq = 0; gq < 4; ++gq) {
        float a = 0.f;
        #pragma unroll
        for (int gp = 0; gp < 4; ++gp)
            #pragma unroll
            for (int x3 = 0; x3 < 4; ++x3)
                a += Mb[gq * 64 + gp * 4 + x3] * C[gp][x3];
        stw(D, WAb + gq * 16384, a);
    }
}

// Row 5, phase 3: fused (5,4)+(5,5); thread 0 -> amplitude.
__device__ __forceinline__ float r5c(const float* __restrict__ S, fcp Ma,
                                     fcp Mb, const int* __restrict__ RA)
{
    float in_[4][4][4];                    // [g][x5=q][x4]
    #pragma unroll
    for (int g = 0; g < 4; ++g)
        #pragma unroll
        for (int q = 0; q < 4; ++q) {
            float4 v = ldq(S, RA[q] + g * 16384);
            in_[g][q][0] = v.x; in_[g][q][1] = v.y;
            in_[g][q][2] = v.z; in_[g][q][3] = v.w;
        }
    float E[4][4];                         // [gp][x5]
    #pragma unroll
    for (int gp = 0; gp < 4; ++gp)
        #pragma unroll
        for (int x5 = 0; x5 < 4; ++x5) {
            float a = 0.f;
            #pragma unroll
            for (int g = 0; g < 4; ++g)
                #pragma unroll
                for (int x4 = 0; x4 < 4; ++x4)
                    a += Ma[gp * 64 + g * 4 + x4] * in_[g][x5][x4];
            E[gp][x5] = a;
        }
    float r = 0.f;
    #pragma unroll
    for (int gp = 0; gp < 4; ++gp)
        #pragma unroll
        for (int x5 = 0; x5 < 4; ++x5)
            r += Mb[gp * 4 + x5] * E[gp][x5];
    return r;
}

// R3: rotation layout + ping-pong (128 KB LDS, 1 block/CU) + pair fusion.
// 17 phases / 17 barriers (was 36 in R1); per-thread LDS addresses RA[4]/WAb
// computed ONCE (R2's regression was per-access swizzle VALU); all fused-pair
// reads are 4x ds_read_b128, all writes scalar with immediate-folded offsets;
// access patterns bank-balanced under SW by construction.
__global__ __launch_bounds__(256, 1)
void peps_amp_kernel(const int* __restrict__ X, const float* __restrict__ Tm,
                     float* __restrict__ out)
{
    __shared__ float W[2][16384];          // 131072 B ping-pong

    const int b = blockIdx.x;
    const int t = threadIdx.x;
    const int* xrow = X + b * NSITE;

    // PHYS=2: pack the 36 spins into one scalar 64-bit mask (SGPR-resident
    // so every Tm address below is provably wave-uniform).
    unsigned long long sm = 0ull;
    const int4* xp = (const int4*)xrow;
    #pragma unroll
    for (int k = 0; k < 9; ++k) {
        int4 v = xp[k];
        sm |= ((unsigned long long)(v.x & 1)) << (4 * k + 0);
        sm |= ((unsigned long long)(v.y & 1)) << (4 * k + 1);
        sm |= ((unsigned long long)(v.z & 1)) << (4 * k + 2);
        sm |= ((unsigned long long)(v.w & 1)) << (4 * k + 3);
    }
    {
        unsigned lo = __builtin_amdgcn_readfirstlane((int)(sm & 0xffffffffull));
        unsigned hi = __builtin_amdgcn_readfirstlane((int)(sm >> 32));
        sm = ((unsigned long long)hi << 32) | lo;
    }

    // Thread-constant rotation-layout addresses (byte offsets).
    int RA[4];
    #pragma unroll
    for (int q = 0; q < 4; ++q) RA[q] = 4 * SW(16 * t + 4 * q);
    const int WAb = 4 * SW(t);

    float* S = &W[0][0];
    float* D = &W[1][0];

    // ---- row 0: 2 phases ----
    if (t < 64) r0a(S, msel(Tm, 0, sm), msel(Tm, 1, sm),
                    msel(Tm, 2, sm), msel(Tm, 3, sm), t);
    __syncthreads();
    r0b(S, D, msel(Tm, 4, sm), msel(Tm, 5, sm), WAb);
    { float* tmp = S; S = D; D = tmp; }    // state in W[1]

    // ---- rows 1..4: 3 fused phases each ----
    #pragma unroll 1
    for (int row = 1; row <= 4; ++row) {
        const int s0 = row * 6;
        __syncthreads();
        p1_mid(S, D, msel(Tm, s0, sm), msel(Tm, s0 + 1, sm), RA, WAb);
        { float* tmp = S; S = D; D = tmp; }
        __syncthreads();
        p2_mid<false>(S, D, msel(Tm, s0 + 2, sm), msel(Tm, s0 + 3, sm), RA, WAb);
        { float* tmp = S; S = D; D = tmp; }
        __syncthreads();
        p2_mid<true>(S, D, msel(Tm, s0 + 4, sm), msel(Tm, s0 + 5, sm), RA, WAb);
        { float* tmp = S; S = D; D = tmp; }
    }

    // ---- row 5: 3 phases ----
    __syncthreads();
    r5a(S, D, msel(Tm, 30, sm), msel(Tm, 31, sm), RA, WAb);
    { float* tmp = S; S = D; D = tmp; }
    __syncthreads();
    if (t < 16) r5b(S, D, msel(Tm, 32, sm), msel(Tm, 33, sm), RA, WAb);
    { float* tmp = S; S = D; D = tmp; }
    __syncthreads();
    if (t == 0) out[b] = r5c(S, msel(Tm, 34, sm), msel(Tm, 35, sm), RA);
}

extern "C" void kernel_launch(void* const* d_in, const int* in_sizes, int n_in,
                              void* d_out, int out_size, void* d_ws, size_t ws_size,
                              hipStream_t stream) {
    const int*   X  = (const int*)d_in[0];     // x: [1024, 36] int32
    const float* Tg = (const float*)d_in[1];   // T: [6,6,2,4,4,4,4] fp32
    float* out = (float*)d_out;                // reference output: float32
    float* Tm  = (float*)d_ws;                 // 73,728 B scratch
    (void)in_sizes; (void)n_in; (void)ws_size; (void)out_size;
    peps_reorder_kernel<<<dim3(72), dim3(256), 0, stream>>>(Tg, Tm);
    peps_amp_kernel<<<dim3(BATCH), dim3(256), 0, stream>>>(X, Tm, out);
}

// Round 4
// 207.244 us; speedup vs baseline: 1.3113x; 1.3113x over previous
//
#include <hip/hip_runtime.h>

#define NROW 6
#define NCOL 6
#define BATCH 1024
#define NSITE 36

// LDS bank-conflict swizzle: XOR dword-addr bits [4:2] with bits [7:5].
// Preserves bits [1:0]; constant within any aligned 4-dword window; SWZ(0)==0.
__device__ __forceinline__ int SWZ(int a) { return a ^ (((a >> 5) & 7) << 2); }

// R4: M matrices come from LDS (uniform-address ds_read broadcast), not SMEM.
// R0..R3 all pinned SGPR_Count at the 112 cap: the compiler could hold only
// ~2-3 of the 16 M rows per phase in SGPRs and serialized
// s_load->waitcnt->consume->reload through the whole FMA stream (~3K cyc
// stall per wave per phase — the 55-75% idle seen in every round). LDS
// broadcast reads have ~120 cyc latency, pipeline freely, and cost no SGPRs.

// Stage row 'row''s six spin-selected 16x16 matrices from T (global) into
// registers; the transpose T[st][sp][x][gp][z][g] -> M[(gp*4+z)*16 + g*4 + x]
// is inlined (kills the separate reorder kernel + its launch gap).
// Thread t holds dst word w=t of each site's 256-float matrix.
__device__ __forceinline__ void stage_load(const float* __restrict__ T,
                                           unsigned long long sm, int row,
                                           int t, float* __restrict__ mst)
{
    #pragma unroll
    for (int k = 0; k < 6; ++k) {
        const int st = row * 6 + k;
        const int spin = (int)((sm >> st) & 1ull);
        const int w = t;                       // dst word: gp*64+z*16+g*4+x
        const int src = (st * 2 + spin) * 256 + (w & 3) * 64
                      + ((w >> 6) & 3) * 16 + ((w >> 4) & 3) * 4
                      + ((w >> 2) & 3);
        mst[k] = T[src];
    }
}

__device__ __forceinline__ void stage_write(float* __restrict__ Mrow,
                                            int t, const float* __restrict__ mst)
{
    #pragma unroll
    for (int k = 0; k < 6; ++k) Mrow[k * 256 + t] = mst[k];  // stride-1: 2-way, free
}

// One step body, 4 SPECTATORS PER THREAD (u = 4t..4t+3), fully specialized,
// one divergent branch — verbatim R0 structure (harness-verified) except the
// M operand now reads LDS via uniform-address float4 (broadcast, no SGPR
// pressure). Spectator quads are LDS-contiguous for all ZS==4 and C0 steps
// -> all state traffic is ds_read_b128/ds_write_b128; 4 independent FMA
// chains (ILP).
template<int GIN, int GOUT, int XS, int ZS, bool C0>
__device__ __forceinline__ void do_step4(float* __restrict__ W,
                                         const float* __restrict__ Ml,
                                         const int* __restrict__ A, int p4c,
                                         bool act)
{
    if (!act) return;
    float in_s[4][16];           // [spectator][g*4+x]
    // ---- read phase ----
    if (C0) {                    // GIN==1; x (or z) is the low address digit
        if (XS == 4) {
            #pragma unroll
            for (int i = 0; i < 4; ++i) {
                float4 q = *(const float4*)&W[A[i]];
                in_s[i][0] = q.x; in_s[i][1] = q.y;
                in_s[i][2] = q.z; in_s[i][3] = q.w;
            }
        } else {
            #pragma unroll
            for (int i = 0; i < 4; ++i) in_s[i][0] = W[A[i]];
        }
    } else if (ZS == 4) {        // spectator quad contiguous at A[x]
        #pragma unroll
        for (int g = 0; g < GIN; ++g)
            #pragma unroll
            for (int x = 0; x < XS; ++x) {
                float4 q = *(const float4*)&W[A[x] + g * 4096];
                in_s[0][g*4+x] = q.x; in_s[1][g*4+x] = q.y;
                in_s[2][g*4+x] = q.z; in_s[3][g*4+x] = q.w;
            }
    } else {                     // row5 c>=1: scattered scalars (tiny work)
        #pragma unroll
        for (int g = 0; g < GIN; ++g)
            #pragma unroll
            for (int x = 0; x < XS; ++x)
                #pragma unroll
                for (int i = 0; i < 4; ++i)
                    in_s[i][g*4+x] = W[SWZ(x * p4c + A[i]) + g * 4096];
    }
    // ---- compute + write (in-place; same address set) ----
    #pragma unroll
    for (int gp = 0; gp < GOUT; ++gp) {
        float a[ZS][4];
        #pragma unroll
        for (int z = 0; z < ZS; ++z) {
            const int mb = (gp * 4 + z) * 16;
            #pragma unroll
            for (int i = 0; i < 4; ++i) a[z][i] = 0.f;
            #pragma unroll
            for (int g = 0; g < GIN; ++g) {
                float mv[4];
                if (XS == 4) {   // uniform ds_read_b128 broadcast (16B-aligned)
                    float4 mq = *(const float4*)&Ml[mb + g * 4];
                    mv[0] = mq.x; mv[1] = mq.y; mv[2] = mq.z; mv[3] = mq.w;
                } else {
                    mv[0] = Ml[mb + g * 4];
                }
                #pragma unroll
                for (int x = 0; x < XS; ++x) {
                    const float m = mv[x];
                    #pragma unroll
                    for (int i = 0; i < 4; ++i)
                        a[z][i] += m * in_s[i][g*4+x];
                }
            }
        }
        if (C0 && ZS == 4) {
            #pragma unroll
            for (int i = 0; i < 4; ++i)
                *(float4*)&W[A[i] + gp * 4096] =
                    make_float4(a[0][i], a[1][i], a[2][i], a[3][i]);
        } else if (ZS == 4) {
            #pragma unroll
            for (int z = 0; z < 4; ++z)
                *(float4*)&W[A[z] + gp * 4096] =
                    make_float4(a[z][0], a[z][1], a[z][2], a[z][3]);
        } else if (C0) {         // row5 c0: z collapses, base address
            #pragma unroll
            for (int i = 0; i < 4; ++i) W[A[i] + gp * 4096] = a[0][i];
        } else {                 // row5 c>=1
            #pragma unroll
            for (int i = 0; i < 4; ++i) W[SWZ(A[i]) + gp * 4096] = a[0][i];
        }
    }
}

// Fixed-slot in-place contraction (verified R8..R16 + R0 algebra): state
// index = g*4096 + sum_j slot_j*4^j; step (row,c) reads up-bond x from slot c
// and writes down-bond z back into the same slot. ONE barrier/step. State in
// LDS (64 KB, swizzled) + 12 KB double-buffered M rows = 77.8 KB -> 2
// blocks/CU, 8 waves/CU. scount=1 steps: (0,0)'s stray spectator writes land
// in W[4..15](+gp*4096), fully overwritten by step (0,1) before (0,2) reads
// them; (5,5) is last (only W[0] read). M staging is T14-split: global loads
// issued at row start, LDS writes at phase (row,5), consumed from row+1 on.
__global__ __launch_bounds__(256, 2)
void peps_amp_kernel(const int* __restrict__ X, const float* __restrict__ T,
                     float* __restrict__ out)
{
    __shared__ float W[16384];        // 65536 B (4^7 fixed-slot state)
    __shared__ float Mb[2][6][256];   // 12288 B: per-row spin-selected M, x2

    const int b = blockIdx.x;
    const int t = threadIdx.x;
    const int u0 = 4 * t;             // this thread's spectators: u0..u0+3
    const int* xrow = X + b * NSITE;

    // PHYS=2: pack the 36 spins into one scalar 64-bit mask (SGPR-resident
    // so staging addresses below are wave-uniform computable).
    unsigned long long sm = 0ull;
    const int4* xp = (const int4*)xrow;
    #pragma unroll
    for (int k = 0; k < 9; ++k) {
        int4 v = xp[k];
        sm |= ((unsigned long long)(v.x & 1)) << (4 * k + 0);
        sm |= ((unsigned long long)(v.y & 1)) << (4 * k + 1);
        sm |= ((unsigned long long)(v.z & 1)) << (4 * k + 2);
        sm |= ((unsigned long long)(v.w & 1)) << (4 * k + 3);
    }
    {
        unsigned lo = __builtin_amdgcn_readfirstlane((int)(sm & 0xffffffffull));
        unsigned hi = __builtin_amdgcn_readfirstlane((int)(sm >> 32));
        sm = ((unsigned long long)hi << 32) | lo;
    }

    // ---- prologue: stage row 0's matrices; seed the state ----
    float mst[6];
    stage_load(T, sm, 0, t, mst);
    stage_write(&Mb[0][0][0], t, mst);
    if (t == 0) W[0] = 1.0f;          // SWZ(0)==0; covered by step-0 barrier

    int step = 0;
    for (int row = 0; row < NROW; ++row) {
        const int xs = (row == 0) ? 1 : 4;          // up-bond size
        const int zs = (row == NROW - 1) ? 1 : 4;   // down-bond size
        const bool haveNext = (row + 1 < NROW);
        if (haveNext) stage_load(T, sm, row + 1, t, mst);  // issue early (T14)

        for (int c = 0; c < NCOL; ++c, ++step) {
            const int lowb  = (zs == 4) ? 2 * c : 0;
            const int highb = (xs == 4) ? 2 * (5 - c) : 0;
            const int scount = 1 << (lowb + highb);
            const int p4c = 1 << (2 * c);
            const int lowmask = (1 << lowb) - 1;
            const bool act = (u0 < scount);

            __syncthreads();     // the ONLY barrier per step

            // write next row's M late — loads landed ~5 phases ago; the
            // (row+1,0) barrier orders these writes before their readers.
            if (c == NCOL - 1 && haveNext)
                stage_write(&Mb[(row + 1) & 1][0][0], t, mst);

            const float* Ml = &Mb[row & 1][c][0];

            // per-thread LDS addresses (quad-aligned where vectorized)
            int A[4];
            if (c == 0) {
                #pragma unroll
                for (int i = 0; i < 4; ++i) A[i] = SWZ(16 * t + 4 * i);
            } else if (zs == 4) {
                const int mr0 = ((u0 >> lowb) << (2 * c + 2)) | (u0 & lowmask);
                #pragma unroll
                for (int d = 0; d < 4; ++d) A[d] = SWZ(d * p4c + mr0);
            } else {             // row5 c>=1: per-spectator bases, unswizzled
                #pragma unroll
                for (int i = 0; i < 4; ++i) A[i] = (u0 + i) << (2 * c + 2);
            }

            // uniform 3x3 dispatch to branch-free specialized bodies
            if (row == 0) {
                if (c == 0)            do_step4<1,4,1,4,true >(W, Ml, A, p4c, act);
                else if (c < NCOL - 1) do_step4<4,4,1,4,false>(W, Ml, A, p4c, act);
                else                   do_step4<4,1,1,4,false>(W, Ml, A, p4c, act);
            } else if (row < NROW - 1) {
                if (c == 0)            do_step4<1,4,4,4,true >(W, Ml, A, p4c, act);
                else if (c < NCOL - 1) do_step4<4,4,4,4,false>(W, Ml, A, p4c, act);
                else                   do_step4<4,1,4,4,false>(W, Ml, A, p4c, act);
            } else {
                if (c == 0)            do_step4<1,4,4,1,true >(W, Ml, A, p4c, act);
                else if (c < NCOL - 1) do_step4<4,4,4,1,false>(W, Ml, A, p4c, act);
                else                   do_step4<4,1,4,1,false>(W, Ml, A, p4c, act);
            }
        }
    }
    __syncthreads();
    // after (5,5): only g'=0, z=0, u=0 live -> the amplitude sits at W[0]
    if (t == 0) out[b] = W[0];
}

extern "C" void kernel_launch(void* const* d_in, const int* in_sizes, int n_in,
                              void* d_out, int out_size, void* d_ws, size_t ws_size,
                              hipStream_t stream) {
    const int*   X  = (const int*)d_in[0];     // x: [1024, 36] int32
    const float* Tg = (const float*)d_in[1];   // T: [6,6,2,4,4,4,4] fp32
    float* out = (float*)d_out;                // reference output: float32
    (void)in_sizes; (void)n_in; (void)ws_size; (void)out_size; (void)d_ws;
    // single kernel: the T transpose is inlined into per-row M staging
    peps_amp_kernel<<<dim3(BATCH), dim3(256), 0, stream>>>(X, Tg, out);
}

// Round 5
// 204.644 us; speedup vs baseline: 1.3280x; 1.0127x over previous
//
#include <hip/hip_runtime.h>

#define NROW 6
#define NCOL 6
#define BATCH 1024
#define NSITE 36

// LDS bank-conflict swizzle: XOR dword-addr bits [4:2] with bits [7:5].
// Preserves bits [1:0]; constant within any aligned 4-dword window; SWZ(0)==0.
__device__ __forceinline__ int SWZ(int a) { return a ^ (((a >> 5) & 7) << 2); }

// Wave-uniform scalar-memory pointer: address_space(4) = AMDGPU constant.
// Scalar float loads at uniform offsets merge into s_load_dwordx4/x16 (SMEM
// pipe, one fetch per wave) — R12 (prior session) proved this path.
// R4 disproved the "SGPR-starvation" theory: M belongs HERE, not in LDS.
typedef const float __attribute__((address_space(4))) * fcp;

// R5: packed fp32. v2f maps to a VGPR pair; elementwise fma on it selects
// v_pk_fma_f32 on gfx950 (VOP3P packed-fp32), halving the scalar-FMA issue
// stream that is the measured 69us floor. Spectator quads already sit in
// consecutive VGPRs after ds_read_b128, so lo/hi packing is zero-shuffle.
typedef float v2f __attribute__((ext_vector_type(2)));
typedef float v4f __attribute__((ext_vector_type(4)));

__device__ __forceinline__ v2f fma2(v2f m, v2f x, v2f a) {
#if __has_builtin(__builtin_elementwise_fma)
    return __builtin_elementwise_fma(m, x, a);
#else
    v2f r; r[0] = fmaf(m[0], x[0], a[0]); r[1] = fmaf(m[1], x[1], a[1]);
    return r;
#endif
}
__device__ __forceinline__ v2f lo2(v4f q) { return __builtin_shufflevector(q, q, 0, 1); }
__device__ __forceinline__ v2f hi2(v4f q) { return __builtin_shufflevector(q, q, 2, 3); }
__device__ __forceinline__ v4f cat4(v2f l, v2f h) { return __builtin_shufflevector(l, h, 0, 1, 2, 3); }

// Pre-transpose T[site][spin][u=x][r=gp][d=z][l=g] into
// Tm[(site*2+spin)*256 + (gp*4+z)*16 + (g*4+x)]  (73,728 B in d_ws).
__global__ void peps_reorder_kernel(const float* __restrict__ T,
                                    float* __restrict__ Tm)
{
    int idx = blockIdx.x * 256 + threadIdx.x;   // [0, 18432)
    if (idx >= NSITE * 2 * 256) return;
    int i  = idx & 15;          // i = g*4 + x
    int o  = (idx >> 4) & 15;   // o = gp*4 + z
    int sp = (idx >> 8) & 1;
    int st = idx >> 9;
    int g = i >> 2, x = i & 3, gp = o >> 2, z = o & 3;
    Tm[idx] = T[st * 512 + sp * 256 + x * 64 + gp * 16 + z * 4 + g];
}

// One step body, 4 SPECTATORS PER THREAD (u = 4t..4t+3) packed as two v2f
// lanes {u0,u1},{u2,u3}; fully specialized, one divergent branch. Identical
// arithmetic/order to the verified R0 body — only the FMA packing changed.
// in2[h][g*4+x] = spectators {2h, 2h+1} of state element (g,x).
template<int GIN, int GOUT, int XS, int ZS, bool C0>
__device__ __forceinline__ void do_step4(float* __restrict__ W, const fcp Msf,
                                         const int* __restrict__ A, int p4c,
                                         bool act)
{
    if (!act) return;
    v2f in2[2][16];
    // ---- read phase ----
    if (C0) {                    // GIN==1; x (or z) is the low address digit
        if (XS == 4) {           // per-spectator x-quads -> transpose to pairs
            v4f q0 = *(const v4f*)&W[A[0]];
            v4f q1 = *(const v4f*)&W[A[1]];
            v4f q2 = *(const v4f*)&W[A[2]];
            v4f q3 = *(const v4f*)&W[A[3]];
            #pragma unroll
            for (int x = 0; x < 4; ++x) {
                v2f a, b;
                a[0] = q0[x]; a[1] = q1[x]; in2[0][x] = a;
                b[0] = q2[x]; b[1] = q3[x]; in2[1][x] = b;
            }
        } else {
            v2f a, b;
            a[0] = W[A[0]]; a[1] = W[A[1]]; in2[0][0] = a;
            b[0] = W[A[2]]; b[1] = W[A[3]]; in2[1][0] = b;
        }
    } else if (ZS == 4) {        // spectator quad contiguous at A[x]: free pack
        #pragma unroll
        for (int g = 0; g < GIN; ++g)
            #pragma unroll
            for (int x = 0; x < XS; ++x) {
                v4f q = *(const v4f*)&W[A[x] + g * 4096];
                in2[0][g*4+x] = lo2(q);
                in2[1][g*4+x] = hi2(q);
            }
    } else {                     // row5 c>=1: scattered scalars (tiny work)
        #pragma unroll
        for (int g = 0; g < GIN; ++g)
            #pragma unroll
            for (int x = 0; x < XS; ++x) {
                v2f a, b;
                a[0] = W[SWZ(x * p4c + A[0]) + g * 4096];
                a[1] = W[SWZ(x * p4c + A[1]) + g * 4096];
                b[0] = W[SWZ(x * p4c + A[2]) + g * 4096];
                b[1] = W[SWZ(x * p4c + A[3]) + g * 4096];
                in2[0][g*4+x] = a; in2[1][g*4+x] = b;
            }
    }
    // ---- compute + write (in-place; same address set) ----
    #pragma unroll
    for (int gp = 0; gp < GOUT; ++gp) {
        v2f a2[ZS][2];
        #pragma unroll
        for (int z = 0; z < ZS; ++z) {
            const int mb = (gp * 4 + z) * 16;
            a2[z][0] = (v2f)0.f; a2[z][1] = (v2f)0.f;
            #pragma unroll
            for (int g = 0; g < GIN; ++g)
                #pragma unroll
                for (int x = 0; x < XS; ++x) {
                    const float m = Msf[mb + g * 4 + x];
                    v2f m2; m2[0] = m; m2[1] = m;     // op_sel broadcast
                    a2[z][0] = fma2(m2, in2[0][g*4+x], a2[z][0]);
                    a2[z][1] = fma2(m2, in2[1][g*4+x], a2[z][1]);
                }
        }
        if (C0 && ZS == 4) {     // transpose back: one quad per spectator
            #pragma unroll
            for (int i = 0; i < 4; ++i) {
                v4f r;
                r[0] = a2[0][i >> 1][i & 1];
                r[1] = a2[1][i >> 1][i & 1];
                r[2] = a2[2][i >> 1][i & 1];
                r[3] = a2[3][i >> 1][i & 1];
                *(v4f*)&W[A[i] + gp * 4096] = r;
            }
        } else if (ZS == 4) {    // pairs re-concatenate for free
            #pragma unroll
            for (int z = 0; z < 4; ++z)
                *(v4f*)&W[A[z] + gp * 4096] = cat4(a2[z][0], a2[z][1]);
        } else if (C0) {         // row5 c0: z collapses, base address
            #pragma unroll
            for (int i = 0; i < 4; ++i)
                W[A[i] + gp * 4096] = a2[0][i >> 1][i & 1];
        } else {                 // row5 c>=1
            #pragma unroll
            for (int i = 0; i < 4; ++i)
                W[SWZ(A[i]) + gp * 4096] = a2[0][i >> 1][i & 1];
        }
    }
}

// Fixed-slot in-place contraction (verified R8..R16 + R0 algebra): state
// index = g*4096 + sum_j slot_j*4^j; step (row,c) reads up-bond x from slot c
// and writes down-bond z back into the same slot. ONE barrier/step. State in
// LDS (64 KB, swizzled). scount=1 steps: (0,0)'s stray spectator writes land
// in W[4..15](+gp*4096), fully overwritten by step (0,1) before (0,2) reads
// them; (5,5) is last (only W[0] read). 256 threads x 4 spectators; 2
// blocks/CU (LDS-bound), 8 waves/CU.
__global__ __launch_bounds__(256, 2)
void peps_amp_kernel(const int* __restrict__ X, const float* __restrict__ Tm,
                     float* __restrict__ out)
{
    __shared__ float W[16384];   // 65536 B exactly (4^7 fixed-slot state)

    const int b = blockIdx.x;
    const int t = threadIdx.x;
    const int u0 = 4 * t;        // this thread's spectators: u0..u0+3
    const int* xrow = X + b * NSITE;

    // PHYS=2: pack the 36 spins into one scalar 64-bit mask (SGPR-resident
    // so every Tm address below is provably wave-uniform).
    unsigned long long sm = 0ull;
    const int4* xp = (const int4*)xrow;
    #pragma unroll
    for (int k = 0; k < 9; ++k) {
        int4 v = xp[k];
        sm |= ((unsigned long long)(v.x & 1)) << (4 * k + 0);
        sm |= ((unsigned long long)(v.y & 1)) << (4 * k + 1);
        sm |= ((unsigned long long)(v.z & 1)) << (4 * k + 2);
        sm |= ((unsigned long long)(v.w & 1)) << (4 * k + 3);
    }
    {
        unsigned lo = __builtin_amdgcn_readfirstlane((int)(sm & 0xffffffffull));
        unsigned hi = __builtin_amdgcn_readfirstlane((int)(sm >> 32));
        sm = ((unsigned long long)hi << 32) | lo;
    }

    if (t == 0) W[0] = 1.0f;     // seed (SWZ(0)==0); covered by step-0 barrier

    int step = 0;
    for (int row = 0; row < NROW; ++row) {
        const int xs = (row == 0) ? 1 : 4;          // up-bond size
        const int zs = (row == NROW - 1) ? 1 : 4;   // down-bond size
        for (int c = 0; c < NCOL; ++c, ++step) {
            const int lowb  = (zs == 4) ? 2 * c : 0;
            const int highb = (xs == 4) ? 2 * (5 - c) : 0;
            const int scount = 1 << (lowb + highb);
            const int p4c = 1 << (2 * c);
            const int lowmask = (1 << lowb) - 1;
            const bool act = (u0 < scount);

            // uniform scalar: spin bit + M base for this step (SMEM pointer)
            const int spin = (int)((sm >> step) & 1ull);
            const fcp Msf = (fcp)(unsigned long long)
                (const void*)(Tm + (size_t)(step * 2 + spin) * 256);

            __syncthreads();     // the ONLY barrier per step

            // per-thread LDS addresses (quad-aligned where vectorized)
            int A[4];
            if (c == 0) {
                #pragma unroll
                for (int i = 0; i < 4; ++i) A[i] = SWZ(16 * t + 4 * i);
            } else if (zs == 4) {
                const int mr0 = ((u0 >> lowb) << (2 * c + 2)) | (u0 & lowmask);
                #pragma unroll
                for (int d = 0; d < 4; ++d) A[d] = SWZ(d * p4c + mr0);
            } else {             // row5 c>=1: per-spectator bases, unswizzled
                #pragma unroll
                for (int i = 0; i < 4; ++i) A[i] = (u0 + i) << (2 * c + 2);
            }

            // uniform 3x3 dispatch to branch-free specialized bodies
            if (row == 0) {
                if (c == 0)            do_step4<1,4,1,4,true >(W, Msf, A, p4c, act);
                else if (c < NCOL - 1) do_step4<4,4,1,4,false>(W, Msf, A, p4c, act);
                else                   do_step4<4,1,1,4,false>(W, Msf, A, p4c, act);
            } else if (row < NROW - 1) {
                if (c == 0)            do_step4<1,4,4,4,true >(W, Msf, A, p4c, act);
                else if (c < NCOL - 1) do_step4<4,4,4,4,false>(W, Msf, A, p4c, act);
                else                   do_step4<4,1,4,4,false>(W, Msf, A, p4c, act);
            } else {
                if (c == 0)            do_step4<1,4,4,1,true >(W, Msf, A, p4c, act);
                else if (c < NCOL - 1) do_step4<4,4,4,1,false>(W, Msf, A, p4c, act);
                else                   do_step4<4,1,4,1,false>(W, Msf, A, p4c, act);
            }
        }
    }
    __syncthreads();
    // after (5,5): only g'=0, z=0, u=0 live -> the amplitude sits at W[0]
    if (t == 0) out[b] = W[0];
}

extern "C" void kernel_launch(void* const* d_in, const int* in_sizes, int n_in,
                              void* d_out, int out_size, void* d_ws, size_t ws_size,
                              hipStream_t stream) {
    const int*   X  = (const int*)d_in[0];     // x: [1024, 36] int32
    const float* Tg = (const float*)d_in[1];   // T: [6,6,2,4,4,4,4] fp32
    float* out = (float*)d_out;                // reference output: float32
    float* Tm  = (float*)d_ws;                 // 73,728 B scratch
    (void)in_sizes; (void)n_in; (void)ws_size; (void)out_size;
    peps_reorder_kernel<<<dim3(72), dim3(256), 0, stream>>>(Tg, Tm);
    peps_amp_kernel<<<dim3(BATCH), dim3(256), 0, stream>>>(X, Tm, out);
}